// Round 4
// baseline (445.989 us; speedup 1.0000x reference)
//
#include <hip/hip_runtime.h>
#include <math.h>

// ---------------------------------------------------------------------------
// Grok5PhiCore: out = proj( softmax(QK^T*scale + phi_bias) V ).
// B=2, L=2048, D=1024, H=16, Dh=64.
//
// v10 (attn: no-LDS, no-barrier main loop):
//  - K/V per head (256 KB each) is L2-resident => LDS staging + barriers were
//    pure overhead (v6-v9 all bound by the lockstep structure, not by any
//    pipe). Waves now read MFMA fragments DIRECTLY from global/L2 and
//    free-run; zero barriers in the main loop, zero LDS bank conflicts.
//  - V stored TILE-MAJOR [jt 32][d 64][j 64 permuted] so the 8 fragment
//    loads per 32-j chunk fold into 3 pointers + immediate offsets.
//  - wave = 16 q x 1024 j (j-parity split); block = 4 waves (2 q-strips x
//    2 j-parities; parities read complementary 64B halves of each V line,
//    strips read identical K/V streams -> L1 completes/reuses lines).
//  - grid 2048 blocks, XCD-decode groups 4 heads per XCD (2 MB K/V in L2).
//  - j-half partial combine via 8.3 KB LDS at the end (only sync left).
//  - bias as QK C-init, phi positions advanced by fract(+64*phi) per chunk.
//  - GEMMs/prep unchanged; v_transpose now writes tile-major V.
//
// Workspace (48 MB, fp16):
//   xb    [4096][1024]   8 MB   x cast
//   wqkvT [3072][1024]   6 MB   w_qkv transposed
//   wpT   [1024][1024]   2 MB   w_proj transposed
//   qb    [32][2048][64] 8 MB   Q per head, PRE-SCALED by 0.125*log2e
//   kb    [32][2048][64] 8 MB   K per head
//   vb    [32][32][64][64] 8 MB V per head, tile-major, j-permuted
//   ctx   [4096][1024]   8 MB   dual-use: V l-major staging, then attn output
// ---------------------------------------------------------------------------

typedef _Float16 f16;
typedef _Float16 f16x4 __attribute__((ext_vector_type(4)));
typedef _Float16 f16x8 __attribute__((ext_vector_type(8)));
typedef float f32x4 __attribute__((ext_vector_type(4)));

#define MFMA32(a, b, c) __builtin_amdgcn_mfma_f32_16x16x32_f16(a, b, c, 0, 0, 0)

static constexpr int Bsz = 2, Lseq = 2048, Dm = 1024, H = 16, Dh = 64;
static constexpr int Mtot = Bsz * Lseq;        // 4096
static constexpr int NQKV = 3 * Dm;            // 3072
static constexpr float PHI_F = 1.61803398874989484820f;
static constexpr float LOG2E = 1.44269504088896f;
static constexpr float QS = 0.125f * LOG2E;    // folded into stored q
static constexpr float CSTEP = 0.55417527999932633f;   // fract(64*phi)
static constexpr float C16 = 0.88854381999831757f;     // fract(16*phi)

// async 16B global -> LDS (lds dest = wave-uniform base + lane*16)
__device__ __forceinline__ void load16_to_lds(const f16* g, f16* l) {
  __builtin_amdgcn_global_load_lds(
      (const __attribute__((address_space(1))) unsigned int*)g,
      (__attribute__((address_space(3))) unsigned int*)l, 16, 0, 0);
}

// ---------------- prep: fp32 -> fp16 cast (4 elems/thread) -----------------
__global__ __launch_bounds__(256) void cast_f32_f16(const float* __restrict__ in,
                                                    f16* __restrict__ out, int n) {
  int i = (blockIdx.x * 256 + threadIdx.x) * 4;
  if (i < n) {
    float4 v = *reinterpret_cast<const float4*>(in + i);
    f16 t[4] = {(f16)v.x, (f16)v.y, (f16)v.z, (f16)v.w};
    *reinterpret_cast<uint2*>(out + i) = *reinterpret_cast<uint2*>(t);
  }
}

// ------------- prep: transpose+cast  in[K][N] fp32 -> out[N][K] fp16 -------
__global__ __launch_bounds__(256) void transpose_cast(const float* __restrict__ in,
                                                      f16* __restrict__ out,
                                                      int K, int N) {
  __shared__ float tile[32][33];
  int n0 = blockIdx.x * 32, k0 = blockIdx.y * 32;
  int tx = threadIdx.x & 31, ty = threadIdx.x >> 5;  // 32 x 8
#pragma unroll
  for (int r = 0; r < 32; r += 8)
    tile[ty + r][tx] = in[(size_t)(k0 + ty + r) * N + n0 + tx];
  __syncthreads();
#pragma unroll
  for (int r = 0; r < 32; r += 8)
    out[(size_t)(n0 + ty + r) * K + k0 + tx] = (f16)tile[tx][ty + r];
}

// --- prep: V l-major [BH][L][64] -> tile-major [BH][jt][64 d][64 j-perm] ---
// Within each 64-j tile: chunk c = jh*4+qd (8 f16) of row d holds j-slots
// {jh*32+qd*4+r, jh*32+16+qd*4+r}  (the K=32 PV A-frag permutation).
__global__ __launch_bounds__(256) void v_transpose(const f16* __restrict__ in,
                                                   f16* __restrict__ out) {
  __shared__ f16 td[64][68];  // [d][l], pad 4
  int bh = blockIdx.y, l0 = blockIdx.x * 64;
  int tid = threadIdx.x;
  const f16* src = in + (size_t)bh * Lseq * Dh;
#pragma unroll
  for (int c = tid; c < 512; c += 256) {
    int row = c >> 3, col = (c & 7) * 8;  // row = l, col = d
    uint4 v = *reinterpret_cast<const uint4*>(src + (size_t)(l0 + row) * Dh + col);
    f16 tmp[8];
    *reinterpret_cast<uint4*>(tmp) = v;
#pragma unroll
    for (int j = 0; j < 8; j++) td[col + j][row] = tmp[j];
  }
  __syncthreads();
  // tile-major output: [bh][jt = l0/64][d][64]
  f16* dst = out + (size_t)bh * Dh * Lseq + (size_t)(l0 >> 6) * 4096;
#pragma unroll
  for (int c = tid; c < 512; c += 256) {
    int d = c >> 3, co = c & 7;
    int jh = co >> 2, qd = co & 3;
    f16 tmp[8];
#pragma unroll
    for (int e = 0; e < 4; e++) tmp[e] = td[d][jh * 32 + qd * 4 + e];
#pragma unroll
    for (int e = 0; e < 4; e++) tmp[4 + e] = td[d][jh * 32 + 16 + qd * 4 + e];
    *reinterpret_cast<uint4*>(dst + d * 64 + co * 8) =
        *reinterpret_cast<uint4*>(tmp);
  }
}

// ---------------- GEMM: C[M,N] = A[M,K] * Bt[N,K]^T  (fp16, fp32 acc) ------
// m97-style: global_load_lds(16B) staging, BK=64, unpadded LDS with
// global-side XOR chunk swizzle. MODE 0: 128x128 tile, QKV scatter epilogue.
// MODE 1: 64x128 tile, fp32 out + bias.
template <int MODE>
__global__ __launch_bounds__(256) void gemm_f16(
    const f16* __restrict__ A, const f16* __restrict__ Bt,
    int M, int N, int K,
    f16* __restrict__ qb, f16* __restrict__ kb, f16* __restrict__ vl,
    float* __restrict__ out, const float* __restrict__ bias) {
  constexpr int BM = (MODE == 0) ? 128 : 64;
  constexpr int MI = BM / 32;          // m-frags per wave (4 or 2)
  constexpr int AI = BM / 32;          // A staging iters per thread (4 or 2)
  __shared__ f16 As[BM * 64];
  __shared__ f16 Bs[128 * 64];

  int tid = threadIdx.x;
  int wave = tid >> 6, lane = tid & 63;
  int quad = lane >> 4, l16 = lane & 15;
  int wm = (wave >> 1) * (MI * 16), wn = (wave & 1) * 64;

  // XCD-locality swizzle (1-D grid)
  int lid = blockIdx.x;
  int xcd = lid & 7, t = lid >> 3;
  int m0, n0;
  if (MODE == 0) {  // 32m x 24n blocks; XCD region = 8m x 12n
    int mg = xcd >> 1, ng = xcd & 1;
    m0 = (mg * 8 + t / 12) * 128;
    n0 = (ng * 12 + t % 12) * 128;
  } else {          // 64m x 8n blocks; XCD region = 8m x 8n
    m0 = (xcd * 8 + (t >> 3)) * 64;
    n0 = (t & 7) * 128;
  }

  // staging: lds chunk (64*it + lane) holds global chunk gu of row
  // (8*it + lane>>3), gu = (lane&7) ^ (lane>>3)
  const int gu = (lane & 7) ^ (lane >> 3);
  const f16* gA[AI];
  f16* lA[AI];
#pragma unroll
  for (int i = 0; i < AI; i++) {
    int it = wave * AI + i;
    gA[i] = A + (size_t)(m0 + it * 8 + (lane >> 3)) * K + gu * 8;
    lA[i] = As + it * 512;
  }
  const f16* gB[4];
  f16* lB[4];
#pragma unroll
  for (int i = 0; i < 4; i++) {
    int it = wave * 4 + i;
    gB[i] = Bt + (size_t)(n0 + it * 8 + (lane >> 3)) * K + gu * 8;
    lB[i] = Bs + it * 512;
  }

  f32x4 acc[MI][4] = {};

  for (int k0 = 0; k0 < K; k0 += 64) {
#pragma unroll
    for (int i = 0; i < AI; i++) load16_to_lds(gA[i] + k0, lA[i]);
#pragma unroll
    for (int i = 0; i < 4; i++) load16_to_lds(gB[i] + k0, lB[i]);
    __syncthreads();  // drains vmcnt before barrier
#pragma unroll
    for (int s = 0; s < 2; s++) {
      f16x8 a[MI], b[4];
#pragma unroll
      for (int i = 0; i < MI; i++) {
        int row = wm + i * 16 + l16;
        a[i] = *reinterpret_cast<const f16x8*>(
            As + row * 64 + (((s * 4 + quad) ^ (l16 & 7)) * 8));
      }
#pragma unroll
      for (int j = 0; j < 4; j++) {
        int row = wn + j * 16 + l16;
        b[j] = *reinterpret_cast<const f16x8*>(
            Bs + row * 64 + (((s * 4 + quad) ^ (l16 & 7)) * 8));
      }
#pragma unroll
      for (int i = 0; i < MI; i++)
#pragma unroll
        for (int j = 0; j < 4; j++)
          acc[i][j] = MFMA32(a[i], b[j], acc[i][j]);
    }
    __syncthreads();
  }

  // epilogue: C/D layout col = lane&15, row = quad*4 + reg
#pragma unroll
  for (int i = 0; i < MI; i++) {
#pragma unroll
    for (int j = 0; j < 4; j++) {
      int n = n0 + wn + j * 16 + l16;
#pragma unroll
      for (int r = 0; r < 4; r++) {
        int m = m0 + wm + i * 16 + quad * 4 + r;
        if (MODE == 0) {
          int ty = n >> 10;  // 0=q 1=k 2=v
          int df = n & 1023;
          int h = df >> 6, dh = df & 63;
          int b = m >> 11, l = m & 2047;
          size_t idx = (((size_t)(b * H + h)) * Lseq + l) * Dh + dh;
          if (ty == 0)
            qb[idx] = (f16)(acc[i][j][r] * QS);
          else if (ty == 1)
            kb[idx] = (f16)acc[i][j][r];
          else
            vl[idx] = (f16)acc[i][j][r];
        } else {
          out[(size_t)m * N + n] = acc[i][j][r] + bias[n];
        }
      }
    }
  }
}

// ---------------- flash attention v10 (direct-from-L2, barrier-free) -------
// grid: 2048 blocks x 256 thr. Block decode: xcd = id&7, t = id>>3,
// bh = (t>>6)*8 + xcd (4 heads per XCD), q0 = (t&63)*32.
// Wave w: strip = w>>1 (16 q), jhalf = w&1 (j-chunk parity). Each wave
// processes 32 chunks of 32 j (stride 64), reading K/V frags directly from
// global (L2-resident). No LDS, no barriers until the final j-half combine.
__global__ __launch_bounds__(256, 6) void attn_kernel(
    const f16* __restrict__ qb,   // [BH][L][64], pre-scaled by QS
    const f16* __restrict__ kb,   // [BH][L][64]
    const f16* __restrict__ vb,   // [BH][32 jt][64 d][64 j-perm]
    f16* __restrict__ ctx) {      // [B*L][1024]
  __shared__ __align__(16) unsigned char smem[8448];

  int id = blockIdx.x;
  int xcd = id & 7, t = id >> 3;
  int bh = ((t >> 6) << 3) + xcd;
  int q0 = (t & 63) * 32;

  int tid = threadIdx.x, wave = tid >> 6, lane = tid & 63;
  int quad = lane >> 4, l16 = lane & 15;
  int strip = wave >> 1, jhalf = wave & 1;

  // Q B-frags for this wave's 16 q rows (q = q0 + strip*16 + l16):
  // B[k=quad*8+t][n=l16] = Q[q][s*32 + quad*8 + t]
  int q = q0 + strip * 16 + l16;
  const f16* Qrow = qb + ((size_t)bh * Lseq + q) * Dh;
  f16x8 qfrag0 = *reinterpret_cast<const f16x8*>(Qrow + quad * 8);
  f16x8 qfrag1 = *reinterpret_cast<const f16x8*>(Qrow + 32 + quad * 8);
  float pq = fmodf((float)q * PHI_F, 1.0f);

  // phi positions for this wave's first chunk: j = jhalf*32 + jg*16 + quad*4+r
  // pk1 (jg=1) derived per chunk from pk0 via fract(+16*phi).
  float pk0[4];
#pragma unroll
  for (int r = 0; r < 4; r++) {
    int j = jhalf * 32 + quad * 4 + r;
    pk0[r] = fmodf((float)j * PHI_F, 1.0f);
  }

  // direct global fragment pointers (f16 units; imm offsets do the rest)
  // K frag (s, jg): pK + s*32 + jg*1024        (advance 4096/chunk = 64 rows)
  // V frag dblk:    pVa + (dblk&1)*1024, pVb likewise (pVb = pVa + 2048)
  const f16* pK = kb + (size_t)bh * Lseq * Dh + (size_t)(jhalf * 32 + l16) * 64 +
                  quad * 8;
  const f16* pVa = vb + (size_t)bh * Dh * Lseq + (size_t)l16 * 64 +
                   jhalf * 32 + quad * 8;
  const f16* pVb = pVa + 2048;

  const f16 one = (f16)1.0f;
  const f16x8 ones8 = {one, one, one, one, one, one, one, one};

  f32x4 acc_o[4] = {};  // [dblk]  O^T partial: row d=dblk*16+quad*4+r, col q
  f32x4 acc_l = {};     // row sums via ones-MFMA

#pragma unroll 1
  for (int it = 0; it < 32; ++it) {
    // K fragments for this 32-j chunk (rows j0.., j0+16..; d-halves s=0,1)
    f16x8 kf00 = *reinterpret_cast<const f16x8*>(pK);
    f16x8 kf01 = *reinterpret_cast<const f16x8*>(pK + 32);
    f16x8 kf10 = *reinterpret_cast<const f16x8*>(pK + 1024);
    f16x8 kf11 = *reinterpret_cast<const f16x8*>(pK + 1056);

    // bias C-init: accs = -log2e*|pq - pk|
    f32x4 accs0, accs1;
    float pk1[4];
#pragma unroll
    for (int r = 0; r < 4; r++) {
      accs0[r] = -LOG2E * fabsf(pq - pk0[r]);
      pk1[r] = __builtin_amdgcn_fractf(pk0[r] + C16);
    }
#pragma unroll
    for (int r = 0; r < 4; r++) {
      accs1[r] = -LOG2E * fabsf(pq - pk1[r]);
      pk0[r] = __builtin_amdgcn_fractf(pk0[r] + CSTEP);  // next chunk (+64 j)
    }

    // S^T = K * Q^T (accumulates onto bias C-init)
    accs0 = MFMA32(kf00, qfrag0, accs0);
    accs0 = MFMA32(kf01, qfrag1, accs0);
    accs1 = MFMA32(kf10, qfrag0, accs1);
    accs1 = MFMA32(kf11, qfrag1, accs1);

    // p = exp2(accs); pack K=32 PV B-frag (permuted k-order:
    // slot (quad,t) -> j = (t<4 ? quad*4+t : 16+quad*4+(t-4)))
    f16x8 pf8;
    {
      float p0 = __builtin_amdgcn_exp2f(accs0[0]);
      float p1 = __builtin_amdgcn_exp2f(accs0[1]);
      float p2 = __builtin_amdgcn_exp2f(accs0[2]);
      float p3 = __builtin_amdgcn_exp2f(accs0[3]);
      auto lo = __builtin_amdgcn_cvt_pkrtz(p0, p1);
      auto hi = __builtin_amdgcn_cvt_pkrtz(p2, p3);
      pf8[0] = lo[0]; pf8[1] = lo[1]; pf8[2] = hi[0]; pf8[3] = hi[1];
      p0 = __builtin_amdgcn_exp2f(accs1[0]);
      p1 = __builtin_amdgcn_exp2f(accs1[1]);
      p2 = __builtin_amdgcn_exp2f(accs1[2]);
      p3 = __builtin_amdgcn_exp2f(accs1[3]);
      lo = __builtin_amdgcn_cvt_pkrtz(p0, p1);
      hi = __builtin_amdgcn_cvt_pkrtz(p2, p3);
      pf8[4] = lo[0]; pf8[5] = lo[1]; pf8[6] = hi[0]; pf8[7] = hi[1];
    }
    acc_l = MFMA32(ones8, pf8, acc_l);

    // V fragments (loaded late to cap register pressure) + PV
    f16x8 va0 = *reinterpret_cast<const f16x8*>(pVa);
    f16x8 va1 = *reinterpret_cast<const f16x8*>(pVa + 1024);
    f16x8 va2 = *reinterpret_cast<const f16x8*>(pVb);
    f16x8 va3 = *reinterpret_cast<const f16x8*>(pVb + 1024);
    acc_o[0] = MFMA32(va0, pf8, acc_o[0]);
    acc_o[1] = MFMA32(va1, pf8, acc_o[1]);
    acc_o[2] = MFMA32(va2, pf8, acc_o[2]);
    acc_o[3] = MFMA32(va3, pf8, acc_o[3]);

    pK += 4096;   // +64 j rows
    pVa += 4096;  // +1 j-tile
    pVb += 4096;
  }

  // combine jhalf partials: pure adds (static max => no rescale)
  float* Oex = (float*)smem;             // [2 strip][4 dblk][16 row][16 col]
  float* Lex = (float*)(smem + 8192);    // [2 strip][16]
  if (jhalf == 1) {
#pragma unroll
    for (int dblk = 0; dblk < 4; dblk++)
#pragma unroll
      for (int r = 0; r < 4; r++)
        Oex[((strip * 4 + dblk) * 16 + quad * 4 + r) * 16 + l16] =
            acc_o[dblk][r];
    if (quad == 0) Lex[strip * 16 + l16] = acc_l[0];
  }
  __syncthreads();
  if (jhalf == 0) {
    int b = bh >> 4, h = bh & 15;
    float ltot = acc_l[0] + Lex[strip * 16 + l16];
    float inv = 1.0f / ltot;
    f16* crow = ctx + (size_t)(b * Lseq + q) * Dm + h * 64;
#pragma unroll
    for (int dblk = 0; dblk < 4; dblk++) {
      f16x4 o;
#pragma unroll
      for (int r = 0; r < 4; r++) {
        float full = acc_o[dblk][r] +
            Oex[((strip * 4 + dblk) * 16 + quad * 4 + r) * 16 + l16];
        o[r] = (f16)(full * inv);
      }
      *reinterpret_cast<uint2*>(crow + dblk * 16 + quad * 4) =
          *reinterpret_cast<uint2*>(&o);
    }
  }
}

// ---------------------------------------------------------------------------
extern "C" void kernel_launch(void* const* d_in, const int* in_sizes, int n_in,
                              void* d_out, int out_size, void* d_ws, size_t ws_size,
                              hipStream_t stream) {
  const float* x      = (const float*)d_in[0];  // [2,2048,1024]
  const float* w_qkv  = (const float*)d_in[1];  // [1024,3072]
  const float* w_proj = (const float*)d_in[2];  // [1024,1024]
  const float* b_proj = (const float*)d_in[3];  // [1024]
  float* out = (float*)d_out;                   // [2,2048,1024]

  f16* xb    = (f16*)d_ws;                       // 4096*1024
  f16* wqkvT = xb + (size_t)Mtot * Dm;           // 3072*1024
  f16* wpT   = wqkvT + (size_t)NQKV * Dm;        // 1024*1024
  f16* qb    = wpT + (size_t)Dm * Dm;            // 32*2048*64
  f16* kb    = qb + (size_t)Bsz * H * Lseq * Dh;
  f16* vb    = kb + (size_t)Bsz * H * Lseq * Dh;
  f16* ctx   = vb + (size_t)Bsz * H * Lseq * Dh; // 4096*1024 (dual-use)
  f16* vl    = ctx;                              // V l-major staging

  // prep
  cast_f32_f16<<<(Mtot * Dm) / (256 * 4), 256, 0, stream>>>(x, xb, Mtot * Dm);
  transpose_cast<<<dim3(NQKV / 32, Dm / 32), 256, 0, stream>>>(w_qkv, wqkvT, Dm, NQKV);
  transpose_cast<<<dim3(Dm / 32, Dm / 32), 256, 0, stream>>>(w_proj, wpT, Dm, Dm);

  // QKV GEMM: [4096,1024] x [1024,3072] -> q (scaled), k, v (all l-major)
  gemm_f16<0><<<768, 256, 0, stream>>>(
      xb, wqkvT, Mtot, NQKV, Dm, qb, kb, vl, nullptr, nullptr);

  // V: l-major -> tile-major j-permuted for the attn PV A-frags
  v_transpose<<<dim3(Lseq / 64, Bsz * H), 256, 0, stream>>>(vl, vb);

  // attention (writes ctx, overwriting consumed vl)
  attn_kernel<<<2048, 256, 0, stream>>>(qb, kb, vb, ctx);

  // proj GEMM: [4096,1024] x [1024,1024] + bias (64x128 tiles)
  gemm_f16<1><<<512, 256, 0, stream>>>(
      ctx, wpT, Mtot, Dm, Dm, nullptr, nullptr, nullptr, out, b_proj);
}

// Round 5
// 240.693 us; speedup vs baseline: 1.8529x; 1.8529x over previous
//
#include <hip/hip_runtime.h>
#include <math.h>

// ---------------------------------------------------------------------------
// Grok5PhiCore: out = proj( softmax(QK^T*scale + phi_bias) V ).
// B=2, L=2048, D=1024, H=16, Dh=64.
//
// v11 (attn: barrier-free wave-private LDS staging):
//  - Each wave stages ONLY what it reads (its 32-j K half, 4KB + its j-half
//    of V columns, 4KB) into a wave-PRIVATE 8KB LDS region via its own
//    global_load_lds DMAs => no cooperative staging => ZERO main-loop
//    barriers. Wave-local s_waitcnt vmcnt(4) replaces __syncthreads; waves
//    free-run and decorrelate (v6-v9 convoyed on 2 barriers/tile; v10
//    showed direct scattered L2 reads are TA-bound).
//  - Pipelined single buffer: issue K(t+1) DMA right after K(t) ds_reads
//    retire (lgkmcnt(0)+sched_barrier fences), V(t+1) after V(t) reads;
//    steady state = 8 outstanding, waits at vmcnt(4) => each load covered
//    by >=1 compute phase.
//  - K: v6 8-chunk XOR swizzle (2-way, free). V half-rows: 4-chunk swizzle
//    slot = c ^ ((d>>1)&3) (2-way, free).
//  - V tile-major [jt][64 d][64 j-perm] (v10's contiguous v_transpose).
//  - bias as QK C-init (v8). Epilogue j-half combine = only sync left.
//  - GEMMs/prep unchanged.
//
// Workspace (48 MB, fp16):
//   xb    [4096][1024]   8 MB   x cast
//   wqkvT [3072][1024]   6 MB   w_qkv transposed
//   wpT   [1024][1024]   2 MB   w_proj transposed
//   qb    [32][2048][64] 8 MB   Q per head, PRE-SCALED by 0.125*log2e
//   kb    [32][2048][64] 8 MB   K per head
//   vb    [32][32][64][64] 8 MB V per head, tile-major, j-permuted
//   ctx   [4096][1024]   8 MB   dual-use: V l-major staging, then attn output
// ---------------------------------------------------------------------------

typedef _Float16 f16;
typedef _Float16 f16x4 __attribute__((ext_vector_type(4)));
typedef _Float16 f16x8 __attribute__((ext_vector_type(8)));
typedef float f32x4 __attribute__((ext_vector_type(4)));

#define MFMA32(a, b, c) __builtin_amdgcn_mfma_f32_16x16x32_f16(a, b, c, 0, 0, 0)

static constexpr int Bsz = 2, Lseq = 2048, Dm = 1024, H = 16, Dh = 64;
static constexpr int Mtot = Bsz * Lseq;        // 4096
static constexpr int NQKV = 3 * Dm;            // 3072
static constexpr float PHI_F = 1.61803398874989484820f;
static constexpr float LOG2E = 1.44269504088896f;
static constexpr float QS = 0.125f * LOG2E;    // folded into stored q
static constexpr float CSTEP = 0.55417527999932633f;   // fract(64*phi)

// async 16B global -> LDS (lds dest = wave-uniform base + lane*16)
__device__ __forceinline__ void load16_to_lds(const f16* g, f16* l) {
  __builtin_amdgcn_global_load_lds(
      (const __attribute__((address_space(1))) unsigned int*)g,
      (__attribute__((address_space(3))) unsigned int*)l, 16, 0, 0);
}

// ---------------- prep: fp32 -> fp16 cast (4 elems/thread) -----------------
__global__ __launch_bounds__(256) void cast_f32_f16(const float* __restrict__ in,
                                                    f16* __restrict__ out, int n) {
  int i = (blockIdx.x * 256 + threadIdx.x) * 4;
  if (i < n) {
    float4 v = *reinterpret_cast<const float4*>(in + i);
    f16 t[4] = {(f16)v.x, (f16)v.y, (f16)v.z, (f16)v.w};
    *reinterpret_cast<uint2*>(out + i) = *reinterpret_cast<uint2*>(t);
  }
}

// ------------- prep: transpose+cast  in[K][N] fp32 -> out[N][K] fp16 -------
__global__ __launch_bounds__(256) void transpose_cast(const float* __restrict__ in,
                                                      f16* __restrict__ out,
                                                      int K, int N) {
  __shared__ float tile[32][33];
  int n0 = blockIdx.x * 32, k0 = blockIdx.y * 32;
  int tx = threadIdx.x & 31, ty = threadIdx.x >> 5;  // 32 x 8
#pragma unroll
  for (int r = 0; r < 32; r += 8)
    tile[ty + r][tx] = in[(size_t)(k0 + ty + r) * N + n0 + tx];
  __syncthreads();
#pragma unroll
  for (int r = 0; r < 32; r += 8)
    out[(size_t)(n0 + ty + r) * K + k0 + tx] = (f16)tile[tx][ty + r];
}

// --- prep: V l-major [BH][L][64] -> tile-major [BH][jt][64 d][64 j-perm] ---
// Within each 64-j tile: chunk c = jh*4+qd (8 f16) of row d holds j-slots
// {jh*32+qd*4+r, jh*32+16+qd*4+r}  (the K=32 PV A-frag permutation).
__global__ __launch_bounds__(256) void v_transpose(const f16* __restrict__ in,
                                                   f16* __restrict__ out) {
  __shared__ f16 td[64][68];  // [d][l], pad 4
  int bh = blockIdx.y, l0 = blockIdx.x * 64;
  int tid = threadIdx.x;
  const f16* src = in + (size_t)bh * Lseq * Dh;
#pragma unroll
  for (int c = tid; c < 512; c += 256) {
    int row = c >> 3, col = (c & 7) * 8;  // row = l, col = d
    uint4 v = *reinterpret_cast<const uint4*>(src + (size_t)(l0 + row) * Dh + col);
    f16 tmp[8];
    *reinterpret_cast<uint4*>(tmp) = v;
#pragma unroll
    for (int j = 0; j < 8; j++) td[col + j][row] = tmp[j];
  }
  __syncthreads();
  // tile-major output: [bh][jt = l0/64][d][64]
  f16* dst = out + (size_t)bh * Dh * Lseq + (size_t)(l0 >> 6) * 4096;
#pragma unroll
  for (int c = tid; c < 512; c += 256) {
    int d = c >> 3, co = c & 7;
    int jh = co >> 2, qd = co & 3;
    f16 tmp[8];
#pragma unroll
    for (int e = 0; e < 4; e++) tmp[e] = td[d][jh * 32 + qd * 4 + e];
#pragma unroll
    for (int e = 0; e < 4; e++) tmp[4 + e] = td[d][jh * 32 + 16 + qd * 4 + e];
    *reinterpret_cast<uint4*>(dst + d * 64 + co * 8) =
        *reinterpret_cast<uint4*>(tmp);
  }
}

// ---------------- GEMM: C[M,N] = A[M,K] * Bt[N,K]^T  (fp16, fp32 acc) ------
// m97-style: global_load_lds(16B) staging, BK=64, unpadded LDS with
// global-side XOR chunk swizzle. MODE 0: 128x128 tile, QKV scatter epilogue.
// MODE 1: 64x128 tile, fp32 out + bias.
template <int MODE>
__global__ __launch_bounds__(256) void gemm_f16(
    const f16* __restrict__ A, const f16* __restrict__ Bt,
    int M, int N, int K,
    f16* __restrict__ qb, f16* __restrict__ kb, f16* __restrict__ vl,
    float* __restrict__ out, const float* __restrict__ bias) {
  constexpr int BM = (MODE == 0) ? 128 : 64;
  constexpr int MI = BM / 32;          // m-frags per wave (4 or 2)
  constexpr int AI = BM / 32;          // A staging iters per thread (4 or 2)
  __shared__ f16 As[BM * 64];
  __shared__ f16 Bs[128 * 64];

  int tid = threadIdx.x;
  int wave = tid >> 6, lane = tid & 63;
  int quad = lane >> 4, l16 = lane & 15;
  int wm = (wave >> 1) * (MI * 16), wn = (wave & 1) * 64;

  // XCD-locality swizzle (1-D grid)
  int lid = blockIdx.x;
  int xcd = lid & 7, t = lid >> 3;
  int m0, n0;
  if (MODE == 0) {  // 32m x 24n blocks; XCD region = 8m x 12n
    int mg = xcd >> 1, ng = xcd & 1;
    m0 = (mg * 8 + t / 12) * 128;
    n0 = (ng * 12 + t % 12) * 128;
  } else {          // 64m x 8n blocks; XCD region = 8m x 8n
    m0 = (xcd * 8 + (t >> 3)) * 64;
    n0 = (t & 7) * 128;
  }

  // staging: lds chunk (64*it + lane) holds global chunk gu of row
  // (8*it + lane>>3), gu = (lane&7) ^ (lane>>3)
  const int gu = (lane & 7) ^ (lane >> 3);
  const f16* gA[AI];
  f16* lA[AI];
#pragma unroll
  for (int i = 0; i < AI; i++) {
    int it = wave * AI + i;
    gA[i] = A + (size_t)(m0 + it * 8 + (lane >> 3)) * K + gu * 8;
    lA[i] = As + it * 512;
  }
  const f16* gB[4];
  f16* lB[4];
#pragma unroll
  for (int i = 0; i < 4; i++) {
    int it = wave * 4 + i;
    gB[i] = Bt + (size_t)(n0 + it * 8 + (lane >> 3)) * K + gu * 8;
    lB[i] = Bs + it * 512;
  }

  f32x4 acc[MI][4] = {};

  for (int k0 = 0; k0 < K; k0 += 64) {
#pragma unroll
    for (int i = 0; i < AI; i++) load16_to_lds(gA[i] + k0, lA[i]);
#pragma unroll
    for (int i = 0; i < 4; i++) load16_to_lds(gB[i] + k0, lB[i]);
    __syncthreads();  // drains vmcnt before barrier
#pragma unroll
    for (int s = 0; s < 2; s++) {
      f16x8 a[MI], b[4];
#pragma unroll
      for (int i = 0; i < MI; i++) {
        int row = wm + i * 16 + l16;
        a[i] = *reinterpret_cast<const f16x8*>(
            As + row * 64 + (((s * 4 + quad) ^ (l16 & 7)) * 8));
      }
#pragma unroll
      for (int j = 0; j < 4; j++) {
        int row = wn + j * 16 + l16;
        b[j] = *reinterpret_cast<const f16x8*>(
            Bs + row * 64 + (((s * 4 + quad) ^ (l16 & 7)) * 8));
      }
#pragma unroll
      for (int i = 0; i < MI; i++)
#pragma unroll
        for (int j = 0; j < 4; j++)
          acc[i][j] = MFMA32(a[i], b[j], acc[i][j]);
    }
    __syncthreads();
  }

  // epilogue: C/D layout col = lane&15, row = quad*4 + reg
#pragma unroll
  for (int i = 0; i < MI; i++) {
#pragma unroll
    for (int j = 0; j < 4; j++) {
      int n = n0 + wn + j * 16 + l16;
#pragma unroll
      for (int r = 0; r < 4; r++) {
        int m = m0 + wm + i * 16 + quad * 4 + r;
        if (MODE == 0) {
          int ty = n >> 10;  // 0=q 1=k 2=v
          int df = n & 1023;
          int h = df >> 6, dh = df & 63;
          int b = m >> 11, l = m & 2047;
          size_t idx = (((size_t)(b * H + h)) * Lseq + l) * Dh + dh;
          if (ty == 0)
            qb[idx] = (f16)(acc[i][j][r] * QS);
          else if (ty == 1)
            kb[idx] = (f16)acc[i][j][r];
          else
            vl[idx] = (f16)acc[i][j][r];
        } else {
          out[(size_t)m * N + n] = acc[i][j][r] + bias[n];
        }
      }
    }
  }
}

// ---------------- flash attention v11 (wave-private staging, no barriers) --
// grid: (L/64, B*H), 256 threads. Wave w: qhalf = w&1 (32 q), jhalf = w>>1
// (32 j of each 64-j tile). Each wave DMA-stages its own K half (4KB) and
// V j-half columns (4KB) into a private 8KB LDS region; wave-local
// vmcnt(4)/lgkmcnt(0) waits; zero main-loop barriers.
__global__ __launch_bounds__(256, 4) void attn_kernel(
    const f16* __restrict__ qb,   // [BH][L][64], pre-scaled by QS
    const f16* __restrict__ kb,   // [BH][L][64]
    const f16* __restrict__ vb,   // [BH][32 jt][64 d][64 j-perm]
    f16* __restrict__ ctx) {      // [B*L][1024]
  __shared__ __align__(16) unsigned char smem[32768];

  int bh = blockIdx.y;
  int q0 = blockIdx.x * 64;
  int tid = threadIdx.x, wave = tid >> 6, lane = tid & 63;
  int quad = lane >> 4, l16 = lane & 15;
  int jhalf = wave >> 1, qhalf = wave & 1;

  f16* Kp = (f16*)(smem + wave * 8192);         // [32][64] swizzled (4KB)
  f16* Vp = (f16*)(smem + wave * 8192 + 4096);  // [64][32] swizzled (4KB)

  // Q B-frags (B[k=quad*8+t][n=l16] = Q[q=l16][d=quad*8+t])
  f16x8 qfrag[2][2];
  float pq[2];
#pragma unroll
  for (int set = 0; set < 2; set++) {
    int q = q0 + qhalf * 32 + set * 16 + l16;
    const f16* Qrow = qb + ((size_t)bh * Lseq + q) * Dh;
    qfrag[set][0] = *reinterpret_cast<const f16x8*>(Qrow + quad * 8);
    qfrag[set][1] = *reinterpret_cast<const f16x8*>(Qrow + 32 + quad * 8);
    pq[set] = fmodf((float)q * PHI_F, 1.0f);
  }

  float pk[2][4];
#pragma unroll
  for (int jb = 0; jb < 2; jb++)
#pragma unroll
    for (int r = 0; r < 4; r++) {
      int j = jhalf * 32 + jb * 16 + quad * 4 + r;
      pk[jb][r] = fmodf((float)j * PHI_F, 1.0f);
    }

  // --- wave-private staging pointers ---------------------------------------
  // K: 4 DMAs; local row r = i*8 + (lane>>3) (global jhalf*32 + r);
  //    lds slot s of row r holds global chunk s^(r&7) via gu = (lane&7)^(lane>>3)
  const f16* Kbh = kb + (size_t)bh * Lseq * Dh;
  const f16* Vbh = vb + (size_t)bh * Dh * Lseq;
  const f16* gK[4];
  f16* lK[4];
  const int gu8 = (lane & 7) ^ (lane >> 3);
#pragma unroll
  for (int i = 0; i < 4; i++) {
    gK[i] = Kbh + (size_t)(jhalf * 32 + i * 8 + (lane >> 3)) * 64 + gu8 * 8;
    lK[i] = Kp + i * 512;
  }
  // V (tile-major): 4 DMAs; local row d = i*16 + (lane>>2);
  //    lds slot s (=lane&3) of row d holds global half-chunk s^((d>>1)&3)
  //    => gu4 = (lane&3)^((lane>>3)&3); global chunk = jhalf*4 + gu4
  const f16* gV[4];
  f16* lV[4];
  const int gu4 = (lane & 3) ^ ((lane >> 3) & 3);
#pragma unroll
  for (int i = 0; i < 4; i++) {
    gV[i] = Vbh + (size_t)(i * 16 + (lane >> 2)) * 64 + (jhalf * 4 + gu4) * 8;
    lV[i] = Vp + i * 512;
  }

  // LDS fragment read bases
  // K frag (s, jb): row = jb*16 + l16, slot = (s*4+quad)^(l16&7)
  const f16* kfp0 = Kp + l16 * 64 + ((quad ^ (l16 & 7)) * 8);          // s=0
  const f16* kfp1 = Kp + l16 * 64 + (((4 + quad) ^ (l16 & 7)) * 8);    // s=1
  // V frag dblk: row d = dblk*16 + l16, slot = quad^((l16>>1)&3)
  const f16* vfp = Vp + l16 * 32 + ((quad ^ ((l16 >> 1) & 3)) * 8);

  const f16 one = (f16)1.0f;
  const f16x8 ones8 = {one, one, one, one, one, one, one, one};

  f32x4 acc_o[2][4] = {};  // [set][dblk]  O^T: row d=quad*4+r, col q=l16
  f32x4 acc_l[2] = {};     // row sums via ones-MFMA

  // prologue: stage tile 0 (8 outstanding: K oldest, V newest)
#pragma unroll
  for (int i = 0; i < 4; i++) load16_to_lds(gK[i], lK[i]);
#pragma unroll
  for (int i = 0; i < 4; i++) load16_to_lds(gV[i], lV[i]);
  // advance to next tile (K: 64 rows * 64 f16; V: one 4096-f16 j-tile)
#pragma unroll
  for (int i = 0; i < 4; i++) { gK[i] += 4096; gV[i] += 4096; }

#pragma unroll 1
  for (int t = 0; t < 32; ++t) {
    // K(t) landed (V(t) still in flight)
    asm volatile("s_waitcnt vmcnt(4)" ::: "memory");
    __builtin_amdgcn_sched_barrier(0);
    f16x8 kf00 = *reinterpret_cast<const f16x8*>(kfp0);          // s0 jb0
    f16x8 kf10 = *reinterpret_cast<const f16x8*>(kfp1);          // s1 jb0
    f16x8 kf01 = *reinterpret_cast<const f16x8*>(kfp0 + 1024);   // s0 jb1
    f16x8 kf11 = *reinterpret_cast<const f16x8*>(kfp1 + 1024);   // s1 jb1
    asm volatile("s_waitcnt lgkmcnt(0)" ::: "memory");
    __builtin_amdgcn_sched_barrier(0);
    // K reads retired -> reuse Kp: issue K(t+1) (wave-local, no barrier)
#pragma unroll
    for (int i = 0; i < 4; i++) load16_to_lds(gK[i], lK[i]);
    __builtin_amdgcn_sched_barrier(0);

    // bias C-init: accs = -log2e*|pq - pk|; advance pk to next tile
    f32x4 accs[2][2];
#pragma unroll
    for (int jb = 0; jb < 2; jb++)
#pragma unroll
      for (int r = 0; r < 4; r++) {
        accs[0][jb][r] = -LOG2E * fabsf(pq[0] - pk[jb][r]);
        accs[1][jb][r] = -LOG2E * fabsf(pq[1] - pk[jb][r]);
        pk[jb][r] = __builtin_amdgcn_fractf(pk[jb][r] + CSTEP);
      }

    // S^T = K * Q^T (accumulates onto bias C-init)
    __builtin_amdgcn_s_setprio(1);
#pragma unroll
    for (int set = 0; set < 2; set++) {
      accs[set][0] = MFMA32(kf00, qfrag[set][0], accs[set][0]);
      accs[set][0] = MFMA32(kf10, qfrag[set][1], accs[set][0]);
      accs[set][1] = MFMA32(kf01, qfrag[set][0], accs[set][1]);
      accs[set][1] = MFMA32(kf11, qfrag[set][1], accs[set][1]);
    }
    __builtin_amdgcn_s_setprio(0);

    // p = exp2(accs); pack K=32 PV B-frag (permuted k-order:
    // slot (quad,t) -> j = jhalf*32 + (t<4 ? quad*4+t : 16+quad*4+(t-4)))
    f16x8 pf8[2];
#pragma unroll
    for (int set = 0; set < 2; set++) {
#pragma unroll
      for (int jb = 0; jb < 2; jb++) {
        float p[4];
#pragma unroll
        for (int r = 0; r < 4; r++)
          p[r] = __builtin_amdgcn_exp2f(accs[set][jb][r]);
        auto lo = __builtin_amdgcn_cvt_pkrtz(p[0], p[1]);
        auto hi = __builtin_amdgcn_cvt_pkrtz(p[2], p[3]);
        pf8[set][jb * 4 + 0] = lo[0];
        pf8[set][jb * 4 + 1] = lo[1];
        pf8[set][jb * 4 + 2] = hi[0];
        pf8[set][jb * 4 + 3] = hi[1];
      }
      acc_l[set] = MFMA32(ones8, pf8[set], acc_l[set]);
    }

    // V(t) landed (K(t+1) still in flight)
    asm volatile("s_waitcnt vmcnt(4)" ::: "memory");
    __builtin_amdgcn_sched_barrier(0);
    f16x8 va0 = *reinterpret_cast<const f16x8*>(vfp);
    f16x8 va1 = *reinterpret_cast<const f16x8*>(vfp + 512);
    f16x8 va2 = *reinterpret_cast<const f16x8*>(vfp + 1024);
    f16x8 va3 = *reinterpret_cast<const f16x8*>(vfp + 1536);
    asm volatile("s_waitcnt lgkmcnt(0)" ::: "memory");
    __builtin_amdgcn_sched_barrier(0);
    // V reads retired -> reuse Vp: issue V(t+1); advance pointers
#pragma unroll
    for (int i = 0; i < 4; i++) load16_to_lds(gV[i], lV[i]);
    __builtin_amdgcn_sched_barrier(0);
#pragma unroll
    for (int i = 0; i < 4; i++) { gK[i] += 4096; gV[i] += 4096; }

    // O^T += V^T * P^T
    __builtin_amdgcn_s_setprio(1);
    acc_o[0][0] = MFMA32(va0, pf8[0], acc_o[0][0]);
    acc_o[1][0] = MFMA32(va0, pf8[1], acc_o[1][0]);
    acc_o[0][1] = MFMA32(va1, pf8[0], acc_o[0][1]);
    acc_o[1][1] = MFMA32(va1, pf8[1], acc_o[1][1]);
    acc_o[0][2] = MFMA32(va2, pf8[0], acc_o[0][2]);
    acc_o[1][2] = MFMA32(va2, pf8[1], acc_o[1][2]);
    acc_o[0][3] = MFMA32(va3, pf8[0], acc_o[0][3]);
    acc_o[1][3] = MFMA32(va3, pf8[1], acc_o[1][3]);
    __builtin_amdgcn_s_setprio(0);
  }
  // note: last iteration issued dummy K/V(32) DMAs (read past this head's
  // K/V into adjacent workspace -- allocated, never read). Drain them
  // before the LDS region is reused below.
  asm volatile("s_waitcnt vmcnt(0)" ::: "memory");
  __syncthreads();

  // combine jhalf partials: pure adds (static max => no rescale)
  float* Oex = (float*)smem;              // [2 qhalf][2 set][4 dblk][16][16]
  float* Lex = (float*)(smem + 16384);    // [2 qhalf][2 set][16]
  if (jhalf == 1) {
#pragma unroll
    for (int set = 0; set < 2; set++) {
#pragma unroll
      for (int dblk = 0; dblk < 4; dblk++)
#pragma unroll
        for (int r = 0; r < 4; r++)
          Oex[(((qhalf * 2 + set) * 4 + dblk) * 16 + quad * 4 + r) * 16 + l16] =
              acc_o[set][dblk][r];
      if (quad == 0) Lex[(qhalf * 2 + set) * 16 + l16] = acc_l[set][0];
    }
  }
  __syncthreads();
  if (jhalf == 0) {
    int b = bh >> 4, h = bh & 15;
#pragma unroll
    for (int set = 0; set < 2; set++) {
      float ltot = acc_l[set][0] + Lex[(qhalf * 2 + set) * 16 + l16];
      float inv = 1.0f / ltot;
      int q = q0 + qhalf * 32 + set * 16 + l16;
      f16* crow = ctx + (size_t)(b * Lseq + q) * Dm + h * 64;
#pragma unroll
      for (int dblk = 0; dblk < 4; dblk++) {
        f16x4 o;
#pragma unroll
        for (int r = 0; r < 4; r++) {
          float full = acc_o[set][dblk][r] +
              Oex[(((qhalf * 2 + set) * 4 + dblk) * 16 + quad * 4 + r) * 16 + l16];
          o[r] = (f16)(full * inv);
        }
        *reinterpret_cast<uint2*>(crow + dblk * 16 + quad * 4) =
            *reinterpret_cast<uint2*>(&o);
      }
    }
  }
}

// ---------------------------------------------------------------------------
extern "C" void kernel_launch(void* const* d_in, const int* in_sizes, int n_in,
                              void* d_out, int out_size, void* d_ws, size_t ws_size,
                              hipStream_t stream) {
  const float* x      = (const float*)d_in[0];  // [2,2048,1024]
  const float* w_qkv  = (const float*)d_in[1];  // [1024,3072]
  const float* w_proj = (const float*)d_in[2];  // [1024,1024]
  const float* b_proj = (const float*)d_in[3];  // [1024]
  float* out = (float*)d_out;                   // [2,2048,1024]

  f16* xb    = (f16*)d_ws;                       // 4096*1024
  f16* wqkvT = xb + (size_t)Mtot * Dm;           // 3072*1024
  f16* wpT   = wqkvT + (size_t)NQKV * Dm;        // 1024*1024
  f16* qb    = wpT + (size_t)Dm * Dm;            // 32*2048*64
  f16* kb    = qb + (size_t)Bsz * H * Lseq * Dh;
  f16* vb    = kb + (size_t)Bsz * H * Lseq * Dh;
  f16* ctx   = vb + (size_t)Bsz * H * Lseq * Dh; // 4096*1024 (dual-use)
  f16* vl    = ctx;                              // V l-major staging

  // prep
  cast_f32_f16<<<(Mtot * Dm) / (256 * 4), 256, 0, stream>>>(x, xb, Mtot * Dm);
  transpose_cast<<<dim3(NQKV / 32, Dm / 32), 256, 0, stream>>>(w_qkv, wqkvT, Dm, NQKV);
  transpose_cast<<<dim3(Dm / 32, Dm / 32), 256, 0, stream>>>(w_proj, wpT, Dm, Dm);

  // QKV GEMM: [4096,1024] x [1024,3072] -> q (scaled), k, v (all l-major)
  gemm_f16<0><<<768, 256, 0, stream>>>(
      xb, wqkvT, Mtot, NQKV, Dm, qb, kb, vl, nullptr, nullptr);

  // V: l-major -> tile-major j-permuted for the attn PV A-frags
  v_transpose<<<dim3(Lseq / 64, Bsz * H), 256, 0, stream>>>(vl, vb);

  // attention (writes ctx, overwriting consumed vl)
  attn_kernel<<<dim3(Lseq / 64, Bsz * H), 256, 0, stream>>>(qb, kb, vb, ctx);

  // proj GEMM: [4096,1024] x [1024,1024] + bias (64x128 tiles)
  gemm_f16<1><<<512, 256, 0, stream>>>(
      ctx, wpT, Mtot, Dm, Dm, nullptr, nullptr, nullptr, out, b_proj);
}

// Round 6
// 189.727 us; speedup vs baseline: 2.3507x; 1.2686x over previous
//
#include <hip/hip_runtime.h>
#include <math.h>

// ---------------------------------------------------------------------------
// Grok5PhiCore: out = proj( softmax(QK^T*scale + phi_bias) V ).
// B=2, L=2048, D=1024, H=16, Dh=64.
//
// v12 (fuse V-transpose into QKV GEMM; attn = verified v6 structure):
//  - gemm MODE0 epilogue writes V DIRECTLY in tile-major j-permuted layout
//    [bh][jt][64 d][64 j-perm]: each (i,j) fragment's 4 r-values map to one
//    contiguous 8B run (l is 4-aligned -> chunk/e0 fixed) => single uint2
//    store, cheaper than the old 4x 2B scattered stores. v_transpose kernel
//    and its 16MB round-trip are DELETED.
//  - attn: exact round-0 v6 kernel (best measured, 56.2us) with V staging
//    base switched to tile-major (g8*64 + j0*64); staged bytes identical.
//  - v7-v11 lessons recorded: counted-vmcnt dbuf null; region interleave
//    null; 2.4x occupancy worse (barrier convoy); direct-L2 frags TA-bound;
//    wave-private DMA defeated by compiler vmcnt(0) insertion. v6 structure
//    is the empirical optimum for this decomposition.
//
// Workspace (48 MB, fp16):
//   xb    [4096][1024]   8 MB   x cast
//   wqkvT [3072][1024]   6 MB   w_qkv transposed
//   wpT   [1024][1024]   2 MB   w_proj transposed
//   qb    [32][2048][64] 8 MB   Q per head, PRE-SCALED by 0.125*log2e
//   kb    [32][2048][64] 8 MB   K per head
//   vb    [32][32][64][64] 8 MB V per head, tile-major, j-permuted
//   ctx   [4096][1024]   8 MB   attn output
// ---------------------------------------------------------------------------

typedef _Float16 f16;
typedef _Float16 f16x4 __attribute__((ext_vector_type(4)));
typedef _Float16 f16x8 __attribute__((ext_vector_type(8)));
typedef float f32x4 __attribute__((ext_vector_type(4)));

#define MFMA32(a, b, c) __builtin_amdgcn_mfma_f32_16x16x32_f16(a, b, c, 0, 0, 0)

static constexpr int Bsz = 2, Lseq = 2048, Dm = 1024, H = 16, Dh = 64;
static constexpr int Mtot = Bsz * Lseq;        // 4096
static constexpr int NQKV = 3 * Dm;            // 3072
static constexpr float PHI_F = 1.61803398874989484820f;
static constexpr float LOG2E = 1.44269504088896f;
static constexpr float QS = 0.125f * LOG2E;    // folded into stored q
static constexpr float CSTEP = 0.55417527999932633f;  // fract(64*phi)

// async 16B global -> LDS (lds dest = wave-uniform base + lane*16)
__device__ __forceinline__ void load16_to_lds(const f16* g, f16* l) {
  __builtin_amdgcn_global_load_lds(
      (const __attribute__((address_space(1))) unsigned int*)g,
      (__attribute__((address_space(3))) unsigned int*)l, 16, 0, 0);
}

// ---------------- prep: fp32 -> fp16 cast (4 elems/thread) -----------------
__global__ __launch_bounds__(256) void cast_f32_f16(const float* __restrict__ in,
                                                    f16* __restrict__ out, int n) {
  int i = (blockIdx.x * 256 + threadIdx.x) * 4;
  if (i < n) {
    float4 v = *reinterpret_cast<const float4*>(in + i);
    f16 t[4] = {(f16)v.x, (f16)v.y, (f16)v.z, (f16)v.w};
    *reinterpret_cast<uint2*>(out + i) = *reinterpret_cast<uint2*>(t);
  }
}

// ------------- prep: transpose+cast  in[K][N] fp32 -> out[N][K] fp16 -------
__global__ __launch_bounds__(256) void transpose_cast(const float* __restrict__ in,
                                                      f16* __restrict__ out,
                                                      int K, int N) {
  __shared__ float tile[32][33];
  int n0 = blockIdx.x * 32, k0 = blockIdx.y * 32;
  int tx = threadIdx.x & 31, ty = threadIdx.x >> 5;  // 32 x 8
#pragma unroll
  for (int r = 0; r < 32; r += 8)
    tile[ty + r][tx] = in[(size_t)(k0 + ty + r) * N + n0 + tx];
  __syncthreads();
#pragma unroll
  for (int r = 0; r < 32; r += 8)
    out[(size_t)(n0 + ty + r) * K + k0 + tx] = (f16)tile[tx][ty + r];
}

// ---------------- GEMM: C[M,N] = A[M,K] * Bt[N,K]^T  (fp16, fp32 acc) ------
// m97-style: global_load_lds(16B) staging, BK=64, unpadded LDS with
// global-side XOR chunk swizzle. MODE 0: 128x128 tile, QKV scatter epilogue
// (V written tile-major j-permuted, packed uint2). MODE 1: 64x128, fp32+bias.
template <int MODE>
__global__ __launch_bounds__(256) void gemm_f16(
    const f16* __restrict__ A, const f16* __restrict__ Bt,
    int M, int N, int K,
    f16* __restrict__ qb, f16* __restrict__ kb, f16* __restrict__ vb,
    float* __restrict__ out, const float* __restrict__ bias) {
  constexpr int BM = (MODE == 0) ? 128 : 64;
  constexpr int MI = BM / 32;          // m-frags per wave (4 or 2)
  constexpr int AI = BM / 32;          // A staging iters per thread (4 or 2)
  __shared__ f16 As[BM * 64];
  __shared__ f16 Bs[128 * 64];

  int tid = threadIdx.x;
  int wave = tid >> 6, lane = tid & 63;
  int quad = lane >> 4, l16 = lane & 15;
  int wm = (wave >> 1) * (MI * 16), wn = (wave & 1) * 64;

  // XCD-locality swizzle (1-D grid)
  int lid = blockIdx.x;
  int xcd = lid & 7, t = lid >> 3;
  int m0, n0;
  if (MODE == 0) {  // 32m x 24n blocks; XCD region = 8m x 12n
    int mg = xcd >> 1, ng = xcd & 1;
    m0 = (mg * 8 + t / 12) * 128;
    n0 = (ng * 12 + t % 12) * 128;
  } else {          // 64m x 8n blocks; XCD region = 8m x 8n
    m0 = (xcd * 8 + (t >> 3)) * 64;
    n0 = (t & 7) * 128;
  }

  // staging: lds chunk (64*it + lane) holds global chunk gu of row
  // (8*it + lane>>3), gu = (lane&7) ^ (lane>>3)
  const int gu = (lane & 7) ^ (lane >> 3);
  const f16* gA[AI];
  f16* lA[AI];
#pragma unroll
  for (int i = 0; i < AI; i++) {
    int it = wave * AI + i;
    gA[i] = A + (size_t)(m0 + it * 8 + (lane >> 3)) * K + gu * 8;
    lA[i] = As + it * 512;
  }
  const f16* gB[4];
  f16* lB[4];
#pragma unroll
  for (int i = 0; i < 4; i++) {
    int it = wave * 4 + i;
    gB[i] = Bt + (size_t)(n0 + it * 8 + (lane >> 3)) * K + gu * 8;
    lB[i] = Bs + it * 512;
  }

  f32x4 acc[MI][4] = {};

  for (int k0 = 0; k0 < K; k0 += 64) {
#pragma unroll
    for (int i = 0; i < AI; i++) load16_to_lds(gA[i] + k0, lA[i]);
#pragma unroll
    for (int i = 0; i < 4; i++) load16_to_lds(gB[i] + k0, lB[i]);
    __syncthreads();  // drains vmcnt before barrier
#pragma unroll
    for (int s = 0; s < 2; s++) {
      f16x8 a[MI], b[4];
#pragma unroll
      for (int i = 0; i < MI; i++) {
        int row = wm + i * 16 + l16;
        a[i] = *reinterpret_cast<const f16x8*>(
            As + row * 64 + (((s * 4 + quad) ^ (l16 & 7)) * 8));
      }
#pragma unroll
      for (int j = 0; j < 4; j++) {
        int row = wn + j * 16 + l16;
        b[j] = *reinterpret_cast<const f16x8*>(
            Bs + row * 64 + (((s * 4 + quad) ^ (l16 & 7)) * 8));
      }
#pragma unroll
      for (int i = 0; i < MI; i++)
#pragma unroll
        for (int j = 0; j < 4; j++)
          acc[i][j] = MFMA32(a[i], b[j], acc[i][j]);
    }
    __syncthreads();
  }

  // epilogue: C/D layout col = lane&15, row = quad*4 + reg
#pragma unroll
  for (int i = 0; i < MI; i++) {
#pragma unroll
    for (int j = 0; j < 4; j++) {
      int n = n0 + wn + j * 16 + l16;
      if (MODE == 0) {
        int ty = n >> 10;  // 0=q 1=k 2=v
        int df = n & 1023;
        int h = df >> 6, dh = df & 63;
        int mb = m0 + wm + i * 16 + quad * 4;  // 4-aligned; +r below
        int b = mb >> 11, l = mb & 2047;
        int bhh = b * H + h;
        if (ty == 2) {
          // V tile-major j-permuted: 4 r-values -> one contiguous 8B run.
          // jj = l&63 (4-aligned): jh = jj>>5, rem = jj&31,
          // qd = (rem&15)>>2, e0 = rem>=16 ? 4 : 0; pos = (jh*4+qd)*8+e0+r
          int jj = l & 63;
          int jh = jj >> 5, rem = jj & 31;
          int qd = (rem & 15) >> 2;
          int e0 = (rem >= 16) ? 4 : 0;
          f16x4 tmp;
#pragma unroll
          for (int r = 0; r < 4; r++) tmp[r] = (f16)acc[i][j][r];
          *reinterpret_cast<uint2*>(
              vb + (size_t)bhh * (Dh * Lseq) + (l >> 6) * 4096 + dh * 64 +
              (jh * 4 + qd) * 8 + e0) = *reinterpret_cast<uint2*>(&tmp);
        } else {
          size_t idx = (((size_t)bhh) * Lseq + l) * Dh + dh;
          if (ty == 0) {
#pragma unroll
            for (int r = 0; r < 4; r++)
              qb[idx + (size_t)r * Dh] = (f16)(acc[i][j][r] * QS);
          } else {
#pragma unroll
            for (int r = 0; r < 4; r++)
              kb[idx + (size_t)r * Dh] = (f16)acc[i][j][r];
          }
        }
      } else {
#pragma unroll
        for (int r = 0; r < 4; r++) {
          int m = m0 + wm + i * 16 + quad * 4 + r;
          out[(size_t)m * N + n] = acc[i][j][r] + bias[n];
        }
      }
    }
  }
}

// ---------------- flash attention (v6 structure, tile-major V) -------------
// grid: (L/64, B*H), 256 threads. Wave w: qhalf = w&1 (32 q), jhalf = w>>1
// (32 j of each 64-j tile). K/V staged via global_load_lds DMA (XOR swizzle);
// PV A-frag = one b128 from permuted Vs. Row sums via ones-A MFMA.
__global__ __launch_bounds__(256, 4) void attn_kernel(
    const f16* __restrict__ qb,   // [BH][L][64], pre-scaled by QS
    const f16* __restrict__ kb,   // [BH][L][64]
    const f16* __restrict__ vb,   // [BH][32 jt][64 d][64 j-perm]
    f16* __restrict__ ctx) {      // [B*L][1024]
  __shared__ __align__(16) unsigned char smem[16640];
  f16* Ks = (f16*)smem;           // [64][64] XOR-swizzled chunks
  f16* Vs = (f16*)(smem + 8192);  // [64][64] permuted + XOR-swizzled

  int bh = blockIdx.y;
  int q0 = blockIdx.x * 64;
  int tid = threadIdx.x, wave = tid >> 6, lane = tid & 63;
  int quad = lane >> 4, l16 = lane & 15;
  int jhalf = wave >> 1, qhalf = wave & 1;

  // Q B-frags (B[k=quad*8+t][n=l16] = Q[q=l16][d=quad*8+t])
  f16x8 qfrag[2][2];
  float pq[2];
#pragma unroll
  for (int set = 0; set < 2; set++) {
    int q = q0 + qhalf * 32 + set * 16 + l16;
    const f16* Qrow = qb + ((size_t)bh * Lseq + q) * Dh;
    qfrag[set][0] = *reinterpret_cast<const f16x8*>(Qrow + quad * 8);
    qfrag[set][1] = *reinterpret_cast<const f16x8*>(Qrow + 32 + quad * 8);
    pq[set] = fmodf((float)q * PHI_F, 1.0f);
  }

  float pk[2][4];
#pragma unroll
  for (int jb = 0; jb < 2; jb++)
#pragma unroll
    for (int r = 0; r < 4; r++) {
      int j = jhalf * 32 + jb * 16 + quad * 4 + r;
      pk[jb][r] = fmodf((float)j * PHI_F, 1.0f);
    }

  // staging pointers (global-side XOR swizzle; lds dest = base + lane*16)
  const f16* Kbh = kb + (size_t)bh * Lseq * Dh;
  const f16* Vbh = vb + (size_t)bh * Dh * Lseq;  // tile-major
  const int gu = (lane & 7) ^ (lane >> 3);
  const f16* gK[2];
  const f16* gV[2];
  f16* lK[2];
  f16* lV[2];
#pragma unroll
  for (int i = 0; i < 2; i++) {
    int g8 = (wave * 2 + i) * 8 + (lane >> 3);
    gK[i] = Kbh + (size_t)g8 * Dh + gu * 8;   // + j0*Dh per tile
    gV[i] = Vbh + (size_t)g8 * 64 + gu * 8;   // + j0*64 per tile (tile-major)
    lK[i] = Ks + (wave * 2 + i) * 512;
    lV[i] = Vs + (wave * 2 + i) * 512;
  }

  const f16 one = (f16)1.0f;
  const f16x8 ones8 = {one, one, one, one, one, one, one, one};

  f32x4 acc_o[2][4] = {};  // [set][dblk]  O^T: row d=quad*4+r, col q=l16
  f32x4 acc_l[2] = {};     // row sums via ones-MFMA

  for (int j0 = 0; j0 < Lseq; j0 += 64) {
    __syncthreads();  // prior tile's frag reads complete
#pragma unroll
    for (int i = 0; i < 2; i++) {
      load16_to_lds(gK[i] + (size_t)j0 * Dh, lK[i]);
      load16_to_lds(gV[i] + (size_t)j0 * 64, lV[i]);
    }
    __syncthreads();  // compiler drains vmcnt before barrier

    // S^T = K * Q^T over this wave's 32 j's
    f32x4 accs[2][2] = {};
#pragma unroll
    for (int s = 0; s < 2; s++)
#pragma unroll
      for (int jb = 0; jb < 2; jb++) {
        f16x8 kf = *reinterpret_cast<const f16x8*>(
            Ks + (jhalf * 32 + jb * 16 + l16) * 64 + (((s * 4 + quad) ^ (l16 & 7)) * 8));
        accs[0][jb] = MFMA32(kf, qfrag[0][s], accs[0][jb]);
        accs[1][jb] = MFMA32(kf, qfrag[1][s], accs[1][jb]);
      }

    // p = exp2(s2 - |pq - pk|*log2e); pack K=32 PV B-frag (permuted k-order:
    // slot (quad, t) -> j = jhalf*32 + (t<4 ? quad*4+t : 16+quad*4+(t-4)))
    f16x8 pf8[2];
#pragma unroll
    for (int set = 0; set < 2; set++) {
#pragma unroll
      for (int jb = 0; jb < 2; jb++) {
        float p[4];
#pragma unroll
        for (int r = 0; r < 4; r++) {
          float d = pq[set] - pk[jb][r];
          float arg = fmaf(-LOG2E, fabsf(d), accs[set][jb][r]);
          p[r] = __builtin_amdgcn_exp2f(arg);
        }
        auto lo = __builtin_amdgcn_cvt_pkrtz(p[0], p[1]);
        auto hi = __builtin_amdgcn_cvt_pkrtz(p[2], p[3]);
        pf8[set][jb * 4 + 0] = lo[0];
        pf8[set][jb * 4 + 1] = lo[1];
        pf8[set][jb * 4 + 2] = hi[0];
        pf8[set][jb * 4 + 3] = hi[1];
      }
      acc_l[set] = MFMA32(ones8, pf8[set], acc_l[set]);
    }
#pragma unroll
    for (int jb = 0; jb < 2; jb++)
#pragma unroll
      for (int r = 0; r < 4; r++)
        pk[jb][r] = __builtin_amdgcn_fractf(pk[jb][r] + CSTEP);

    // O^T += V^T * P^T  (A-frag = one b128 from permuted+swizzled Vs)
#pragma unroll
    for (int dblk = 0; dblk < 4; dblk++) {
      int row = dblk * 16 + l16;
      f16x8 va = *reinterpret_cast<const f16x8*>(
          Vs + row * 64 + (((jhalf * 4 + quad) ^ (l16 & 7)) * 8));
      acc_o[0][dblk] = MFMA32(va, pf8[0], acc_o[0][dblk]);
      acc_o[1][dblk] = MFMA32(va, pf8[1], acc_o[1][dblk]);
    }
  }

  // combine jhalf partials: pure adds (static max => no rescale)
  __syncthreads();
  float* Oex = (float*)smem;              // [2 qhalf][2 set][4 dblk][16][16]
  float* Lex = (float*)(smem + 16384);    // [2 qhalf][2 set][16]
  if (jhalf == 1) {
#pragma unroll
    for (int set = 0; set < 2; set++) {
#pragma unroll
      for (int dblk = 0; dblk < 4; dblk++)
#pragma unroll
        for (int r = 0; r < 4; r++)
          Oex[(((qhalf * 2 + set) * 4 + dblk) * 16 + quad * 4 + r) * 16 + l16] =
              acc_o[set][dblk][r];
      if (quad == 0) Lex[(qhalf * 2 + set) * 16 + l16] = acc_l[set][0];
    }
  }
  __syncthreads();
  if (jhalf == 0) {
    int b = bh >> 4, h = bh & 15;
#pragma unroll
    for (int set = 0; set < 2; set++) {
      float ltot = acc_l[set][0] + Lex[(qhalf * 2 + set) * 16 + l16];
      float inv = 1.0f / ltot;
      int q = q0 + qhalf * 32 + set * 16 + l16;
      f16* crow = ctx + (size_t)(b * Lseq + q) * Dm + h * 64;
#pragma unroll
      for (int dblk = 0; dblk < 4; dblk++) {
        f16x4 o;
#pragma unroll
        for (int r = 0; r < 4; r++) {
          float full = acc_o[set][dblk][r] +
              Oex[(((qhalf * 2 + set) * 4 + dblk) * 16 + quad * 4 + r) * 16 + l16];
          o[r] = (f16)(full * inv);
        }
        *reinterpret_cast<uint2*>(crow + dblk * 16 + quad * 4) =
            *reinterpret_cast<uint2*>(&o);
      }
    }
  }
}

// ---------------------------------------------------------------------------
extern "C" void kernel_launch(void* const* d_in, const int* in_sizes, int n_in,
                              void* d_out, int out_size, void* d_ws, size_t ws_size,
                              hipStream_t stream) {
  const float* x      = (const float*)d_in[0];  // [2,2048,1024]
  const float* w_qkv  = (const float*)d_in[1];  // [1024,3072]
  const float* w_proj = (const float*)d_in[2];  // [1024,1024]
  const float* b_proj = (const float*)d_in[3];  // [1024]
  float* out = (float*)d_out;                   // [2,2048,1024]

  f16* xb    = (f16*)d_ws;                       // 4096*1024
  f16* wqkvT = xb + (size_t)Mtot * Dm;           // 3072*1024
  f16* wpT   = wqkvT + (size_t)NQKV * Dm;        // 1024*1024
  f16* qb    = wpT + (size_t)Dm * Dm;            // 32*2048*64
  f16* kb    = qb + (size_t)Bsz * H * Lseq * Dh;
  f16* vb    = kb + (size_t)Bsz * H * Lseq * Dh; // tile-major j-permuted
  f16* ctx   = vb + (size_t)Bsz * H * Lseq * Dh; // 4096*1024 attn output

  // prep
  cast_f32_f16<<<(Mtot * Dm) / (256 * 4), 256, 0, stream>>>(x, xb, Mtot * Dm);
  transpose_cast<<<dim3(NQKV / 32, Dm / 32), 256, 0, stream>>>(w_qkv, wqkvT, Dm, NQKV);
  transpose_cast<<<dim3(Dm / 32, Dm / 32), 256, 0, stream>>>(w_proj, wpT, Dm, Dm);

  // QKV GEMM: [4096,1024] x [1024,3072] -> q (scaled), k, v (v tile-major)
  gemm_f16<0><<<768, 256, 0, stream>>>(
      xb, wqkvT, Mtot, NQKV, Dm, qb, kb, vb, nullptr, nullptr);

  // attention (writes ctx)
  attn_kernel<<<dim3(Lseq / 64, Bsz * H), 256, 0, stream>>>(qb, kb, vb, ctx);

  // proj GEMM: [4096,1024] x [1024,1024] + bias (64x128 tiles)
  gemm_f16<1><<<512, 256, 0, stream>>>(
      ctx, wpT, Mtot, Dm, Dm, nullptr, nullptr, nullptr, out, b_proj);
}

// Round 7
// 180.823 us; speedup vs baseline: 2.4664x; 1.0492x over previous
//
#include <hip/hip_runtime.h>
#include <math.h>

// ---------------------------------------------------------------------------
// Grok5PhiCore: out = proj( softmax(QK^T*scale + phi_bias) V ).
// B=2, L=2048, D=1024, H=16, Dh=64.
//
// v13 (attn 128q blocks + fused prep):
//  - attn: 128-q blocks, 512 thr, 8 waves = 4 q-groups x 2 j-halves.
//    Per-wave inner code IDENTICAL to v6 (32q x 32j per 64-j tile); each
//    staged 8KB K/V tile now feeds 8 waves -> barriers per unit work HALVE,
//    staging DMA traffic halves, grid 512. XCD decode pins 4 heads/XCD
//    (2MB K/V working set fits 4MB per-XCD L2).
//  - prep: cast + both transpose_casts fused into ONE grid-sectioned kernel
//    (removes two dispatch gaps).
//  - QKV GEMM keeps fused V tile-major epilogue (v12); GEMMs unchanged.
//
// Workspace (48 MB, fp16):
//   xb    [4096][1024]   8 MB   x cast
//   wqkvT [3072][1024]   6 MB   w_qkv transposed
//   wpT   [1024][1024]   2 MB   w_proj transposed
//   qb    [32][2048][64] 8 MB   Q per head, PRE-SCALED by 0.125*log2e
//   kb    [32][2048][64] 8 MB   K per head
//   vb    [32][32][64][64] 8 MB V per head, tile-major, j-permuted
//   ctx   [4096][1024]   8 MB   attn output
// ---------------------------------------------------------------------------

typedef _Float16 f16;
typedef _Float16 f16x4 __attribute__((ext_vector_type(4)));
typedef _Float16 f16x8 __attribute__((ext_vector_type(8)));
typedef float f32x4 __attribute__((ext_vector_type(4)));

#define MFMA32(a, b, c) __builtin_amdgcn_mfma_f32_16x16x32_f16(a, b, c, 0, 0, 0)

static constexpr int Bsz = 2, Lseq = 2048, Dm = 1024, H = 16, Dh = 64;
static constexpr int Mtot = Bsz * Lseq;        // 4096
static constexpr int NQKV = 3 * Dm;            // 3072
static constexpr float PHI_F = 1.61803398874989484820f;
static constexpr float LOG2E = 1.44269504088896f;
static constexpr float QS = 0.125f * LOG2E;    // folded into stored q
static constexpr float CSTEP = 0.55417527999932633f;  // fract(64*phi)

// async 16B global -> LDS (lds dest = wave-uniform base + lane*16)
__device__ __forceinline__ void load16_to_lds(const f16* g, f16* l) {
  __builtin_amdgcn_global_load_lds(
      (const __attribute__((address_space(1))) unsigned int*)g,
      (__attribute__((address_space(3))) unsigned int*)l, 16, 0, 0);
}

// ---------------- fused prep: cast + 2 transposes --------------------------
// grid sections: [0,4096) cast x; [4096,7168) transpose w_qkv;
// [7168,8192) transpose w_proj. 256 threads.
__global__ __launch_bounds__(256) void prep_fused(
    const float* __restrict__ x, f16* __restrict__ xb,
    const float* __restrict__ wqkv, f16* __restrict__ wqkvT,
    const float* __restrict__ wproj, f16* __restrict__ wpT) {
  __shared__ float tile[32][33];
  int blk = blockIdx.x;
  if (blk < 4096) {
    int i = (blk * 256 + threadIdx.x) * 4;
    float4 v = *reinterpret_cast<const float4*>(x + i);
    f16 t[4] = {(f16)v.x, (f16)v.y, (f16)v.z, (f16)v.w};
    *reinterpret_cast<uint2*>(xb + i) = *reinterpret_cast<uint2*>(t);
    return;
  }
  const float* in;
  f16* out;
  int N, bx, by;
  if (blk < 7168) {
    int local = blk - 4096;
    bx = local % 96; by = local / 96; N = NQKV;
    in = wqkv; out = wqkvT;
  } else {
    int local = blk - 7168;
    bx = local & 31; by = local >> 5; N = Dm;
    in = wproj; out = wpT;
  }
  int n0 = bx * 32, k0 = by * 32;  // K = Dm always
  int tx = threadIdx.x & 31, ty = threadIdx.x >> 5;  // 32 x 8
#pragma unroll
  for (int r = 0; r < 32; r += 8)
    tile[ty + r][tx] = in[(size_t)(k0 + ty + r) * N + n0 + tx];
  __syncthreads();
#pragma unroll
  for (int r = 0; r < 32; r += 8)
    out[(size_t)(n0 + ty + r) * Dm + k0 + tx] = (f16)tile[tx][ty + r];
}

// ---------------- GEMM: C[M,N] = A[M,K] * Bt[N,K]^T  (fp16, fp32 acc) ------
// m97-style: global_load_lds(16B) staging, BK=64, unpadded LDS with
// global-side XOR chunk swizzle. MODE 0: 128x128 tile, QKV scatter epilogue
// (V written tile-major j-permuted, packed uint2). MODE 1: 64x128, fp32+bias.
template <int MODE>
__global__ __launch_bounds__(256) void gemm_f16(
    const f16* __restrict__ A, const f16* __restrict__ Bt,
    int M, int N, int K,
    f16* __restrict__ qb, f16* __restrict__ kb, f16* __restrict__ vb,
    float* __restrict__ out, const float* __restrict__ bias) {
  constexpr int BM = (MODE == 0) ? 128 : 64;
  constexpr int MI = BM / 32;          // m-frags per wave (4 or 2)
  constexpr int AI = BM / 32;          // A staging iters per thread (4 or 2)
  __shared__ f16 As[BM * 64];
  __shared__ f16 Bs[128 * 64];

  int tid = threadIdx.x;
  int wave = tid >> 6, lane = tid & 63;
  int quad = lane >> 4, l16 = lane & 15;
  int wm = (wave >> 1) * (MI * 16), wn = (wave & 1) * 64;

  // XCD-locality swizzle (1-D grid)
  int lid = blockIdx.x;
  int xcd = lid & 7, t = lid >> 3;
  int m0, n0;
  if (MODE == 0) {  // 32m x 24n blocks; XCD region = 8m x 12n
    int mg = xcd >> 1, ng = xcd & 1;
    m0 = (mg * 8 + t / 12) * 128;
    n0 = (ng * 12 + t % 12) * 128;
  } else {          // 64m x 8n blocks; XCD region = 8m x 8n
    m0 = (xcd * 8 + (t >> 3)) * 64;
    n0 = (t & 7) * 128;
  }

  // staging: lds chunk (64*it + lane) holds global chunk gu of row
  // (8*it + lane>>3), gu = (lane&7) ^ (lane>>3)
  const int gu = (lane & 7) ^ (lane >> 3);
  const f16* gA[AI];
  f16* lA[AI];
#pragma unroll
  for (int i = 0; i < AI; i++) {
    int it = wave * AI + i;
    gA[i] = A + (size_t)(m0 + it * 8 + (lane >> 3)) * K + gu * 8;
    lA[i] = As + it * 512;
  }
  const f16* gB[4];
  f16* lB[4];
#pragma unroll
  for (int i = 0; i < 4; i++) {
    int it = wave * 4 + i;
    gB[i] = Bt + (size_t)(n0 + it * 8 + (lane >> 3)) * K + gu * 8;
    lB[i] = Bs + it * 512;
  }

  f32x4 acc[MI][4] = {};

  for (int k0 = 0; k0 < K; k0 += 64) {
#pragma unroll
    for (int i = 0; i < AI; i++) load16_to_lds(gA[i] + k0, lA[i]);
#pragma unroll
    for (int i = 0; i < 4; i++) load16_to_lds(gB[i] + k0, lB[i]);
    __syncthreads();  // drains vmcnt before barrier
#pragma unroll
    for (int s = 0; s < 2; s++) {
      f16x8 a[MI], b[4];
#pragma unroll
      for (int i = 0; i < MI; i++) {
        int row = wm + i * 16 + l16;
        a[i] = *reinterpret_cast<const f16x8*>(
            As + row * 64 + (((s * 4 + quad) ^ (l16 & 7)) * 8));
      }
#pragma unroll
      for (int j = 0; j < 4; j++) {
        int row = wn + j * 16 + l16;
        b[j] = *reinterpret_cast<const f16x8*>(
            Bs + row * 64 + (((s * 4 + quad) ^ (l16 & 7)) * 8));
      }
#pragma unroll
      for (int i = 0; i < MI; i++)
#pragma unroll
        for (int j = 0; j < 4; j++)
          acc[i][j] = MFMA32(a[i], b[j], acc[i][j]);
    }
    __syncthreads();
  }

  // epilogue: C/D layout col = lane&15, row = quad*4 + reg
#pragma unroll
  for (int i = 0; i < MI; i++) {
#pragma unroll
    for (int j = 0; j < 4; j++) {
      int n = n0 + wn + j * 16 + l16;
      if (MODE == 0) {
        int ty = n >> 10;  // 0=q 1=k 2=v
        int df = n & 1023;
        int h = df >> 6, dh = df & 63;
        int mb = m0 + wm + i * 16 + quad * 4;  // 4-aligned; +r below
        int b = mb >> 11, l = mb & 2047;
        int bhh = b * H + h;
        if (ty == 2) {
          // V tile-major j-permuted: 4 r-values -> one contiguous 8B run.
          int jj = l & 63;
          int jh = jj >> 5, rem = jj & 31;
          int qd = (rem & 15) >> 2;
          int e0 = (rem >= 16) ? 4 : 0;
          f16x4 tmp;
#pragma unroll
          for (int r = 0; r < 4; r++) tmp[r] = (f16)acc[i][j][r];
          *reinterpret_cast<uint2*>(
              vb + (size_t)bhh * (Dh * Lseq) + (l >> 6) * 4096 + dh * 64 +
              (jh * 4 + qd) * 8 + e0) = *reinterpret_cast<uint2*>(&tmp);
        } else {
          size_t idx = (((size_t)bhh) * Lseq + l) * Dh + dh;
          if (ty == 0) {
#pragma unroll
            for (int r = 0; r < 4; r++)
              qb[idx + (size_t)r * Dh] = (f16)(acc[i][j][r] * QS);
          } else {
#pragma unroll
            for (int r = 0; r < 4; r++)
              kb[idx + (size_t)r * Dh] = (f16)acc[i][j][r];
          }
        }
      } else {
#pragma unroll
        for (int r = 0; r < 4; r++) {
          int m = m0 + wm + i * 16 + quad * 4 + r;
          out[(size_t)m * N + n] = acc[i][j][r] + bias[n];
        }
      }
    }
  }
}

// ---------------- flash attention v13 (128-q blocks, 8 waves) --------------
// grid: 512 blocks x 512 thr. Decode: xcd = id&7, t = id>>3,
// bh = xcd*4 + (t>>4) (4 heads/XCD -> 2MB K/V in per-XCD L2),
// q0 = (t&15)*128. Wave w: qq = w&3 (q-group of 32), jhalf = w>>2.
// Per-wave inner code identical to v6; staged tile feeds 8 waves.
__global__ __launch_bounds__(512, 4) void attn_kernel(
    const f16* __restrict__ qb,   // [BH][L][64], pre-scaled by QS
    const f16* __restrict__ kb,   // [BH][L][64]
    const f16* __restrict__ vb,   // [BH][32 jt][64 d][64 j-perm]
    f16* __restrict__ ctx) {      // [B*L][1024]
  __shared__ __align__(16) unsigned char smem[33280];
  f16* Ks = (f16*)smem;           // [64][64] XOR-swizzled chunks
  f16* Vs = (f16*)(smem + 8192);  // [64][64] permuted + XOR-swizzled

  int id = blockIdx.x;
  int bh = (id & 7) * 4 + ((id >> 3) >> 4);
  int q0 = ((id >> 3) & 15) * 128;

  int tid = threadIdx.x, wave = tid >> 6, lane = tid & 63;
  int quad = lane >> 4, l16 = lane & 15;
  int jhalf = wave >> 2, qq = wave & 3;

  // Q B-frags (B[k=quad*8+t][n=l16] = Q[q=l16][d=quad*8+t])
  f16x8 qfrag[2][2];
  float pq[2];
#pragma unroll
  for (int set = 0; set < 2; set++) {
    int q = q0 + qq * 32 + set * 16 + l16;
    const f16* Qrow = qb + ((size_t)bh * Lseq + q) * Dh;
    qfrag[set][0] = *reinterpret_cast<const f16x8*>(Qrow + quad * 8);
    qfrag[set][1] = *reinterpret_cast<const f16x8*>(Qrow + 32 + quad * 8);
    pq[set] = fmodf((float)q * PHI_F, 1.0f);
  }

  float pk[2][4];
#pragma unroll
  for (int jb = 0; jb < 2; jb++)
#pragma unroll
    for (int r = 0; r < 4; r++) {
      int j = jhalf * 32 + jb * 16 + quad * 4 + r;
      pk[jb][r] = fmodf((float)j * PHI_F, 1.0f);
    }

  // staging (1 K-chunk + 1 V-chunk per wave; 8 waves cover the 64-row tile)
  // lds chunk (64*w + lane) holds global chunk gu of row (8w + lane>>3)
  const f16* Kbh = kb + (size_t)bh * Lseq * Dh;
  const f16* Vbh = vb + (size_t)bh * Dh * Lseq;  // tile-major
  const int gu = (lane & 7) ^ (lane >> 3);
  int g8 = wave * 8 + (lane >> 3);
  const f16* gK = Kbh + (size_t)g8 * Dh + gu * 8;  // + j0*Dh per tile
  const f16* gV = Vbh + (size_t)g8 * 64 + gu * 8;  // + j0*64 per tile
  f16* lK = Ks + wave * 512;
  f16* lV = Vs + wave * 512;

  const f16 one = (f16)1.0f;
  const f16x8 ones8 = {one, one, one, one, one, one, one, one};

  f32x4 acc_o[2][4] = {};  // [set][dblk]  O^T: row d=quad*4+r, col q=l16
  f32x4 acc_l[2] = {};     // row sums via ones-MFMA

  for (int j0 = 0; j0 < Lseq; j0 += 64) {
    __syncthreads();  // prior tile's frag reads complete
    load16_to_lds(gK + (size_t)j0 * Dh, lK);
    load16_to_lds(gV + (size_t)j0 * 64, lV);
    __syncthreads();  // compiler drains vmcnt before barrier

    // S^T = K * Q^T over this wave's 32 j's
    f32x4 accs[2][2] = {};
#pragma unroll
    for (int s = 0; s < 2; s++)
#pragma unroll
      for (int jb = 0; jb < 2; jb++) {
        f16x8 kf = *reinterpret_cast<const f16x8*>(
            Ks + (jhalf * 32 + jb * 16 + l16) * 64 + (((s * 4 + quad) ^ (l16 & 7)) * 8));
        accs[0][jb] = MFMA32(kf, qfrag[0][s], accs[0][jb]);
        accs[1][jb] = MFMA32(kf, qfrag[1][s], accs[1][jb]);
      }

    // p = exp2(s2 - |pq - pk|*log2e); pack K=32 PV B-frag (permuted k-order:
    // slot (quad, t) -> j = jhalf*32 + (t<4 ? quad*4+t : 16+quad*4+(t-4)))
    f16x8 pf8[2];
#pragma unroll
    for (int set = 0; set < 2; set++) {
#pragma unroll
      for (int jb = 0; jb < 2; jb++) {
        float p[4];
#pragma unroll
        for (int r = 0; r < 4; r++) {
          float d = pq[set] - pk[jb][r];
          float arg = fmaf(-LOG2E, fabsf(d), accs[set][jb][r]);
          p[r] = __builtin_amdgcn_exp2f(arg);
        }
        auto lo = __builtin_amdgcn_cvt_pkrtz(p[0], p[1]);
        auto hi = __builtin_amdgcn_cvt_pkrtz(p[2], p[3]);
        pf8[set][jb * 4 + 0] = lo[0];
        pf8[set][jb * 4 + 1] = lo[1];
        pf8[set][jb * 4 + 2] = hi[0];
        pf8[set][jb * 4 + 3] = hi[1];
      }
      acc_l[set] = MFMA32(ones8, pf8[set], acc_l[set]);
    }
#pragma unroll
    for (int jb = 0; jb < 2; jb++)
#pragma unroll
      for (int r = 0; r < 4; r++)
        pk[jb][r] = __builtin_amdgcn_fractf(pk[jb][r] + CSTEP);

    // O^T += V^T * P^T  (A-frag = one b128 from permuted+swizzled Vs)
#pragma unroll
    for (int dblk = 0; dblk < 4; dblk++) {
      int row = dblk * 16 + l16;
      f16x8 va = *reinterpret_cast<const f16x8*>(
          Vs + row * 64 + (((jhalf * 4 + quad) ^ (l16 & 7)) * 8));
      acc_o[0][dblk] = MFMA32(va, pf8[0], acc_o[0][dblk]);
      acc_o[1][dblk] = MFMA32(va, pf8[1], acc_o[1][dblk]);
    }
  }

  // combine jhalf partials: pure adds (static max => no rescale)
  __syncthreads();
  float* Oex = (float*)smem;              // [4 qq][2 set][4 dblk][16][16]
  float* Lex = (float*)(smem + 32768);    // [4 qq][2 set][16]
  if (jhalf == 1) {
#pragma unroll
    for (int set = 0; set < 2; set++) {
#pragma unroll
      for (int dblk = 0; dblk < 4; dblk++)
#pragma unroll
        for (int r = 0; r < 4; r++)
          Oex[(((qq * 2 + set) * 4 + dblk) * 16 + quad * 4 + r) * 16 + l16] =
              acc_o[set][dblk][r];
      if (quad == 0) Lex[(qq * 2 + set) * 16 + l16] = acc_l[set][0];
    }
  }
  __syncthreads();
  if (jhalf == 0) {
    int b = bh >> 4, h = bh & 15;
#pragma unroll
    for (int set = 0; set < 2; set++) {
      float ltot = acc_l[set][0] + Lex[(qq * 2 + set) * 16 + l16];
      float inv = 1.0f / ltot;
      int q = q0 + qq * 32 + set * 16 + l16;
      f16* crow = ctx + (size_t)(b * Lseq + q) * Dm + h * 64;
#pragma unroll
      for (int dblk = 0; dblk < 4; dblk++) {
        f16x4 o;
#pragma unroll
        for (int r = 0; r < 4; r++) {
          float full = acc_o[set][dblk][r] +
              Oex[(((qq * 2 + set) * 4 + dblk) * 16 + quad * 4 + r) * 16 + l16];
          o[r] = (f16)(full * inv);
        }
        *reinterpret_cast<uint2*>(crow + dblk * 16 + quad * 4) =
            *reinterpret_cast<uint2*>(&o);
      }
    }
  }
}

// ---------------------------------------------------------------------------
extern "C" void kernel_launch(void* const* d_in, const int* in_sizes, int n_in,
                              void* d_out, int out_size, void* d_ws, size_t ws_size,
                              hipStream_t stream) {
  const float* x      = (const float*)d_in[0];  // [2,2048,1024]
  const float* w_qkv  = (const float*)d_in[1];  // [1024,3072]
  const float* w_proj = (const float*)d_in[2];  // [1024,1024]
  const float* b_proj = (const float*)d_in[3];  // [1024]
  float* out = (float*)d_out;                   // [2,2048,1024]

  f16* xb    = (f16*)d_ws;                       // 4096*1024
  f16* wqkvT = xb + (size_t)Mtot * Dm;           // 3072*1024
  f16* wpT   = wqkvT + (size_t)NQKV * Dm;        // 1024*1024
  f16* qb    = wpT + (size_t)Dm * Dm;            // 32*2048*64
  f16* kb    = qb + (size_t)Bsz * H * Lseq * Dh;
  f16* vb    = kb + (size_t)Bsz * H * Lseq * Dh; // tile-major j-permuted
  f16* ctx   = vb + (size_t)Bsz * H * Lseq * Dh; // 4096*1024 attn output

  // fused prep: cast x + transpose w_qkv + transpose w_proj
  prep_fused<<<8192, 256, 0, stream>>>(x, xb, w_qkv, wqkvT, w_proj, wpT);

  // QKV GEMM: [4096,1024] x [1024,3072] -> q (scaled), k, v (v tile-major)
  gemm_f16<0><<<768, 256, 0, stream>>>(
      xb, wqkvT, Mtot, NQKV, Dm, qb, kb, vb, nullptr, nullptr);

  // attention (writes ctx)
  attn_kernel<<<512, 512, 0, stream>>>(qb, kb, vb, ctx);

  // proj GEMM: [4096,1024] x [1024,1024] + bias (64x128 tiles)
  gemm_f16<1><<<512, 256, 0, stream>>>(
      ctx, wpT, Mtot, Dm, Dm, nullptr, nullptr, nullptr, out, b_proj);
}